// Round 7
// baseline (166.963 us; speedup 1.0000x reference)
//
#include <hip/hip_runtime.h>
#include <stdint.h>

#define B_    32768
#define C_    64
#define D_    8
#define K15_  15
#define K16_  16
#define OUT_  512

typedef _Float16 half4v __attribute__((ext_vector_type(4)));
typedef _Float16 half8  __attribute__((ext_vector_type(8)));
typedef uint32_t uint4v __attribute__((ext_vector_type(4)));

// workspace layout (bytes)
#define AMAP_OFF  0
#define AMAP_SZ   32768                  // uint8 argmax per 15-bit code
#define S64_OFF   32768                  // fp64 S, k-major: S64[c][k][d]
#define S64_SZ    (64 * 15 * 8 * 8)      // 61440
#define T64_OFF   (S64_OFF + S64_SZ)     // 94208
#define T64_SZ    (64 * 15 * 8)          // 7680
#define IDX_OFF   (T64_OFF + T64_SZ)     // 101888
#define IDX_SZ    (B_ * C_)              // 2 MB. pairs mode: idxo unused ->
                                         // region reused for S32/T32.
#define S32_SZ    (64 * 15 * 8 * 4)      // 30720
#define PCT_OFF   (IDX_OFF + IDX_SZ)     // 2199040
#define PCT_SZ    (B_ * 32)              // 1 MB: pcT[p][rg][tr][i]
#define PTAB_OFF  (PCT_OFF + PCT_SZ)     // 3247616 (16B aligned)
#define PTAB_SZ   (32 * 32 * 256 * 16 * 2) // 8388608: P5[p][jc][q][16] fp16
#define WS_NEED   ((size_t)PTAB_OFF + PTAB_SZ)

// global_load_lds, width 16 B: LDS dest is wave-uniform base + lane*16
// (m104/m173) -> LDS layout must be linear in lane order.
__device__ __forceinline__ void gld_lds16(const void* g, void* l) {
    __builtin_amdgcn_global_load_lds(
        (const __attribute__((address_space(1))) void*)g,
        (__attribute__((address_space(3))) void*)l, 16, 0, 0);
}

// acc += (float)f16  via v_fma_mix_f32 (exact: cvt exact, *1.0 exact, fp32 add)
__device__ __forceinline__ void fma_mix_lo(float& acc, uint32_t w, float one) {
    asm("v_fma_mix_f32 %0, %1, %2, %0 op_sel_hi:[1,0,0]"
        : "+v"(acc) : "v"(w), "v"(one));
}
__device__ __forceinline__ void fma_mix_hi(float& acc, uint32_t w, float one) {
    asm("v_fma_mix_f32 %0, %1, %2, %0 op_sel:[1,0,0] op_sel_hi:[1,0,0]"
        : "+v"(acc) : "v"(w), "v"(one));
}

// ---------------------------------------------------------------------------
// k_setup (small): 129 blocks. Blocks 0..127 compute amap; block 128 builds
// S64/T64 (+ S32/T32 fp32 copies when flags&1). P5 build moved to k_codes6.
// ---------------------------------------------------------------------------
__global__ __launch_bounds__(256) void k_setup(const float* __restrict__ H,
                                               const float* __restrict__ S,
                                               const float* __restrict__ T,
                                               uint8_t* __restrict__ amap,
                                               double* __restrict__ S64,
                                               double* __restrict__ T64,
                                               float* __restrict__ S32,
                                               float* __restrict__ T32,
                                               int flags) {
    int gid = blockIdx.x * 256 + threadIdx.x;

    if (blockIdx.x < 128) {
        int code = gid;
        double h[K16_];
#pragma unroll
        for (int j = 0; j < K16_; ++j) h[j] = 0.0;
#pragma unroll
        for (int k = 0; k < K15_; ++k) {
            double s = ((code >> k) & 1) ? 1.0 : -1.0;
#pragma unroll
            for (int j = 0; j < K16_; ++j) h[j] += s * (double)H[k * K16_ + j];
        }
        double best = h[0];
        int bi = 0;
#pragma unroll
        for (int j = 1; j < K16_; ++j) {
            if (h[j] > best) { best = h[j]; bi = j; }
        }
        amap[code] = (uint8_t)bi;
    } else {
        for (int i = threadIdx.x; i < 64 * 15 * 8; i += 256) {
            int c = i / 120;
            int r = i - c * 120;  // r = k*8 + d
            int k = r >> 3;
            int d = r & 7;
            float sv = S[c * 120 + d * 15 + k];
            S64[i] = (double)sv;
            if (flags & 1) S32[i] = sv;
        }
        for (int i = threadIdx.x; i < 64 * 15; i += 256) {
            T64[i] = (double)T[i];
            if (flags & 1) T32[i] = T[i];
        }
    }
}

// ---------------------------------------------------------------------------
// k_codes6: blocks [0,2048) = codes work (batch-group 64 x channel-quarter
// 16); blocks [2048,4096) = P5 pair-table build (moved from k_setup so its
// 32MB L2 streaming overlaps the latency-bound codes phase).
// Codes changes vs v5: BOTH rounds' x loaded upfront (8 float4, pinned via
// empty asm so the compiler can't sink the round-1 loads below round-0
// compute). Numerics unchanged: fp32 dots + fp64 rescue (bit-identical).
// ---------------------------------------------------------------------------
#define XST3 579   // odd -> compute reads 2-way (free)
#define CPAD2 24   // uint16 row pad: 48 B rows -> 8B-aligned b64 end reads
template <int FAST>
__global__ __launch_bounds__(256, 6) void k_codes6(const float* __restrict__ x,
                                                   const double* __restrict__ S64,
                                                   const double* __restrict__ T64,
                                                   const float* __restrict__ S32,
                                                   const float* __restrict__ T32,
                                                   const uint8_t* __restrict__ amap,
                                                   uint8_t* __restrict__ idxo,
                                                   uint8_t* __restrict__ pcT,
                                                   const float* __restrict__ LUT,
                                                   _Float16* __restrict__ P5) {
    __shared__ float xls[8 * XST3];                     // 8 ch x 64 b x 9
    __shared__ alignas(16) uint16_t codesh[64 * CPAD2]; // [batch][local ch]

    if (FAST && blockIdx.x >= 2048) {
        // P5 build: gid bits [p:5][jc:5][q:8][e8:1] -> offset gid*8 halfs
        int gid = (blockIdx.x - 2048) * 256 + threadIdx.x;
        int e8 = gid & 1;
        int q = (gid >> 1) & 255;
        int jc = (gid >> 9) & 31;
        int p = gid >> 14;
        int t0 = q >> 4;
        int t1 = q & 15;
        int j0 = jc * 16 + e8 * 8;
        const float* u = LUT + (size_t)((2 * p) * 16 + t0) * 512 + j0;
        const float* v = LUT + (size_t)((2 * p + 1) * 16 + t1) * 512 + j0;
        float4 u0 = ((const float4*)u)[0];
        float4 u1 = ((const float4*)u)[1];
        float4 v0 = ((const float4*)v)[0];
        float4 v1 = ((const float4*)v)[1];
        half8 w;
        w[0] = (_Float16)(u0.x + v0.x);
        w[1] = (_Float16)(u0.y + v0.y);
        w[2] = (_Float16)(u0.z + v0.z);
        w[3] = (_Float16)(u0.w + v0.w);
        w[4] = (_Float16)(u1.x + v1.x);
        w[5] = (_Float16)(u1.y + v1.y);
        w[6] = (_Float16)(u1.z + v1.z);
        w[7] = (_Float16)(u1.w + v1.w);
        *(half8*)(P5 + (size_t)gid * 8) = w;
        return;
    }

    int bg = blockIdx.x >> 2;        // batch group: rows bg*64 .. +63
    int cq = blockIdx.x & 3;         // channel quarter: channels cq*16 .. +15
    int b0 = bg * 64;
    int lane = threadIdx.x & 63;
    int wv = __builtin_amdgcn_readfirstlane(threadIdx.x >> 6);
    int tid = threadIdx.x;

    // upfront loads: round r covers x columns cq*128 + r*64 + [0,64)
    float4 rgA[4], rgB[4];
#pragma unroll
    for (int t2 = 0; t2 < 4; ++t2) {
        int e = t2 * 256 + tid;
        int b = e >> 4;
        int j4 = e & 15;
        rgA[t2] = *(const float4*)(x + (size_t)(b0 + b) * 512 + cq * 128 +
                                   j4 * 4);
        rgB[t2] = *(const float4*)(x + (size_t)(b0 + b) * 512 + cq * 128 +
                                   64 + j4 * 4);
        asm volatile("" :: "v"(rgB[t2].x));  // pin: don't sink below compute
    }

#pragma unroll
    for (int r = 0; r < 2; ++r) {
#pragma unroll
        for (int t2 = 0; t2 < 4; ++t2) {   // write round r to LDS
            int e = t2 * 256 + tid;
            int b = e >> 4;
            int j4 = e & 15;
            int cl = j4 >> 1;
            int d0 = (j4 & 1) * 4;
            float4 v = (r == 0) ? rgA[t2] : rgB[t2];
            float* dst = &xls[cl * XST3 + b * 9 + d0];
            dst[0] = v.x; dst[1] = v.y; dst[2] = v.z; dst[3] = v.w;
        }
        __syncthreads();   // xls(round r) visible
#pragma unroll
        for (int i = 0; i < 2; ++i) {
            int cl = wv + i * 4;                 // wave-uniform, 0..7
            int c = cq * 16 + r * 8 + cl;        // global channel
            unsigned code = 0;
            if (FAST) {
                const float* Sc = S32 + c * 120;  // k-major: Sc[k*8+d]
                const float* Tc = T32 + c * 15;
                float xf[8];
#pragma unroll
                for (int d = 0; d < 8; ++d)
                    xf[d] = xls[cl * XST3 + lane * 9 + d];
                float pmin = 3.0e38f;
#pragma unroll
                for (int k = 0; k < K15_; ++k) {
                    float p = -Tc[k];
#pragma unroll
                    for (int d = 0; d < 8; ++d)
                        p = fmaf(xf[d], Sc[k * 8 + d], p);
                    code |= (p > 0.f) ? (1u << k) : 0u;
                    pmin = fminf(pmin, fabsf(p));
                }
                if (pmin < 1e-4f) {  // rare: redo channel in fp64
                    const double* Sd = S64 + c * 120;
                    const double* Td = T64 + c * 15;
                    code = 0;
#pragma unroll
                    for (int k = 0; k < K15_; ++k) {
                        double p = -Td[k];
#pragma unroll
                        for (int d = 0; d < 8; ++d)
                            p = fma((double)xf[d], Sd[k * 8 + d], p);
                        code |= (p > 0.0) ? (1u << k) : 0u;
                    }
                }
            } else {
                const double* Sc = S64 + c * 120;
                const double* Tc = T64 + c * 15;
                double xd[8];
#pragma unroll
                for (int d = 0; d < 8; ++d)
                    xd[d] = (double)xls[cl * XST3 + lane * 9 + d];
#pragma unroll
                for (int k = 0; k < K15_; ++k) {
                    double p = -Tc[k];
#pragma unroll
                    for (int d = 0; d < 8; ++d)
                        p = fma(xd[d], Sc[k * 8 + d], p);
                    code |= (p > 0.0) ? (1u << k) : 0u;
                }
            }
            codesh[lane * CPAD2 + r * 8 + cl] = (uint16_t)code;
        }
        __syncthreads();   // xls reads done (r=0: before overwrite) / codesh
    }

    // End phase: thread (bb,sub) owns batch bb, channels cq*16+sub*4..+3.
    int bb = tid >> 2;
    int sub = tid & 3;
    uint64_t cw8 = *(const uint64_t*)&codesh[bb * CPAD2 + sub * 4];  // one b64
    uint16_t cds[4];
    cds[0] = (uint16_t)(cw8 & 0xFFFF);
    cds[1] = (uint16_t)((cw8 >> 16) & 0xFFFF);
    cds[2] = (uint16_t)((cw8 >> 32) & 0xFFFF);
    cds[3] = (uint16_t)(cw8 >> 48);
    uint8_t ids[4];
#pragma unroll
    for (int j = 0; j < 4; ++j) ids[j] = amap[cds[j]];  // 4 indep gathers

    if (FAST) {
        int row = b0 + bb;
        int rg = row >> 10;
        int tr = row & 127;
        int i_ = (row & 1023) >> 7;
        uint8_t* base = pcT + rg * 1024 + tr * 8 + i_;
        int p0 = cq * 8 + sub * 2;
        base[(size_t)p0 * 32768] = (uint8_t)((ids[0] << 4) | ids[1]);
        base[(size_t)(p0 + 1) * 32768] = (uint8_t)((ids[2] << 4) | ids[3]);
    } else {
        uint32_t w0 = (uint32_t)ids[0] | ((uint32_t)ids[1] << 8) |
                      ((uint32_t)ids[2] << 16) | ((uint32_t)ids[3] << 24);
        *(uint32_t*)(idxo + (size_t)(b0 + bb) * 64 + cq * 16 + sub * 4) = w0;
    }
}

// ---------------------------------------------------------------------------
// k_main10: streaming-staged gather, v6 — counted-vmcnt pipeline (T3/T4).
// k_main9's remaining ~30K cy/CU idle = __syncthreads' forced vmcnt(0)
// draining the JUST-issued stage(p+1) every pair. v6:
//   * 3 LDS buffers (24 KB -> 6 blocks/CU); stage(p+2) issued into
//     buf[(p+2)%3], whose last readers (gather(p-1)) all passed this
//     iteration's barrier -> race-free without a second barrier.
//   * raw s_barrier + asm "s_waitcnt vmcnt(2)" (wait stage(p), LEAVE
//     stage(p+1) in flight); tail iteration vmcnt(0). sched_barrier(0)
//     fences both sides (rule #18).
//   * all 32 code-words preloaded to VGPRs (pinned with empty asm so the
//     loads can't be sunk into the loop, which would force a full-latency
//     wait at use); loop fully unrolled -> static indexing (rule #20).
// Gather/accumulate identical to k_main9 (conflict fingerprint ~7.52e6).
// ---------------------------------------------------------------------------
__global__ __launch_bounds__(256, 5) void k_main10(const uint8_t* __restrict__ pcT,
                                                   const _Float16* __restrict__ P5,
                                                   float* __restrict__ out) {
    __shared__ alignas(16) _Float16 slab[3][256 * 16];  // 3 x 8 KB, linear

    int rg5 = blockIdx.x >> 5;   // 0..63, owns rows rg5*512 + i*128 + tr
    int jc = blockIdx.x & 31;
    int t = threadIdx.x;
    int tc = t & 1;        // which 8-half piece of the 16-half chunk
    int tr = t >> 1;       // 0..127
    int lane = t & 63;
    int wv = __builtin_amdgcn_readfirstlane(t >> 6);  // wave-uniform

    // pcT[p][rg][tr][i_]: for row = rg5*512 + i*128 + tr:
    //   rg = rg5>>1, i_ = (rg5&1)*4 + i  -> 4 consecutive bytes
    const uint8_t* cbase = pcT + (rg5 >> 1) * 1024 + tr * 8 + (rg5 & 1) * 4;

    // preload ALL 32 code-words; pin so loads stay in the prologue.
    uint32_t cw[32];
#pragma unroll
    for (int p = 0; p < 32; ++p)
        cw[p] = *(const uint32_t*)(cbase + (size_t)p * 32768);
#pragma unroll
    for (int p = 0; p < 32; ++p) asm volatile("" :: "v"(cw[p]));

    float acc[4][8];
#pragma unroll
    for (int i = 0; i < 4; ++i)
#pragma unroll
        for (int e = 0; e < 8; ++e) acc[i][e] = 0.f;
    float one = 1.0f;

    int hoff = wv * 512 + lane * 8;

    // prologue: stage p=0 and p=1
    {
        const _Float16* g0 = P5 + (size_t)jc * 4096 + hoff;
        gld_lds16(g0, &slab[0][wv * 512]);
        gld_lds16(g0 + 2048, &slab[0][wv * 512 + 2048]);
        const _Float16* g1 = P5 + (size_t)(32 + jc) * 4096 + hoff;
        gld_lds16(g1, &slab[1][wv * 512]);
        gld_lds16(g1 + 2048, &slab[1][wv * 512 + 2048]);
    }

#pragma unroll
    for (int p = 0; p < 32; ++p) {
        // wait stage(p) (2 oldest gld_lds); leave stage(p+1) in flight.
        if (p < 31) asm volatile("s_waitcnt vmcnt(2)");
        else        asm volatile("s_waitcnt vmcnt(0)");
        __builtin_amdgcn_sched_barrier(0);
        __builtin_amdgcn_s_barrier();   // all waves: stage(p) visible,
                                        // gather(p-1) complete
        __builtin_amdgcn_sched_barrier(0);

        if (p < 30) {  // stage(p+2) into the buffer gather(p-1) just freed
            const _Float16* g =
                P5 + (size_t)((p + 2) * 32 + jc) * 4096 + hoff;
            _Float16* d = &slab[(p + 2) % 3][wv * 512];
            gld_lds16(g, d);
            gld_lds16(g + 2048, d + 2048);
        }

        const _Float16* rb = &slab[p % 3][0] + tc * 8;
        uint32_t cw_cur = cw[p];
#pragma unroll
        for (int i = 0; i < 4; ++i) {
            int ci = (int)((cw_cur >> (8 * i)) & 0xFF);
            half8 v = *(const half8*)(rb + ci * 16);  // one ds_read_b128
            uint4v w = __builtin_bit_cast(uint4v, v);
#pragma unroll
            for (int e2 = 0; e2 < 4; ++e2) {
                fma_mix_lo(acc[i][2 * e2], w[e2], one);
                fma_mix_hi(acc[i][2 * e2 + 1], w[e2], one);
            }
        }
    }

#pragma unroll
    for (int i = 0; i < 4; ++i) {
        int row = rg5 * 512 + i * 128 + tr;
        float* o = out + (size_t)row * 512 + jc * 16 + tc * 8;
        float4 w0;
        w0.x = acc[i][0]; w0.y = acc[i][1]; w0.z = acc[i][2]; w0.w = acc[i][3];
        float4 w1;
        w1.x = acc[i][4]; w1.y = acc[i][5]; w1.z = acc[i][6]; w1.w = acc[i][7];
        ((float4*)o)[0] = w0;
        ((float4*)o)[1] = w1;
    }
}

// Fallback (small ws): direct 64-channel gather from fp32 LUT.
__global__ __launch_bounds__(256) void k_main_direct(const uint8_t* __restrict__ idx,
                                                     const float* __restrict__ LUT,
                                                     float* __restrict__ out) {
    int j4 = threadIdx.x & 127;
    int sub = threadIdx.x >> 7;
    int b0 = blockIdx.x * 16 + sub * 8;
    const float4* L4 = (const float4*)LUT;
    for (int r = 0; r < 8; ++r) {
        int b = b0 + r;
        const uint32_t* iw = (const uint32_t*)(idx + (size_t)b * 64);
        float4 acc;
        acc.x = 0.f; acc.y = 0.f; acc.z = 0.f; acc.w = 0.f;
#pragma unroll
        for (int i = 0; i < 16; ++i) {
            uint32_t w = __builtin_amdgcn_readfirstlane(iw[i]);
#pragma unroll
            for (int t = 0; t < 4; ++t) {
                int c = i * 4 + t;
                uint32_t codev = (w >> (8 * t)) & 0xFu;
                float4 v = L4[(size_t)(c * 16 + codev) * 128 + j4];
                acc.x += v.x; acc.y += v.y; acc.z += v.z; acc.w += v.w;
            }
        }
        ((float4*)(out + (size_t)b * 512))[j4] = acc;
    }
}

extern "C" void kernel_launch(void* const* d_in, const int* in_sizes, int n_in,
                              void* d_out, int out_size, void* d_ws, size_t ws_size,
                              hipStream_t stream) {
    const float* x   = (const float*)d_in[0];
    const float* S   = (const float*)d_in[1];
    const float* H   = (const float*)d_in[2];
    const float* T   = (const float*)d_in[3];
    const float* LUT = (const float*)d_in[4];
    float* out = (float*)d_out;

    uint8_t* ws = (uint8_t*)d_ws;
    uint8_t* amap = ws + AMAP_OFF;
    double* S64   = (double*)(ws + S64_OFF);
    double* T64   = (double*)(ws + T64_OFF);
    uint8_t* idxb = ws + IDX_OFF;                  // fallback mode only
    float* S32    = (float*)(ws + IDX_OFF);        // pairs mode only
    float* T32    = (float*)(ws + IDX_OFF + S32_SZ);
    uint8_t* pcTb = ws + PCT_OFF;
    _Float16* P5  = (_Float16*)(ws + PTAB_OFF);

    bool use_pairs = ws_size >= WS_NEED;

    hipLaunchKernelGGL(k_setup, dim3(129), dim3(256), 0, stream,
                       H, S, T, amap, S64, T64, S32, T32, use_pairs ? 1 : 0);
    if (use_pairs) {
        hipLaunchKernelGGL((k_codes6<1>), dim3(4096), dim3(256), 0, stream,
                           x, S64, T64, S32, T32, amap, idxb, pcTb, LUT, P5);
        hipLaunchKernelGGL(k_main10, dim3(2048), dim3(256), 0, stream,
                           pcTb, P5, out);
    } else {
        hipLaunchKernelGGL((k_codes6<0>), dim3(2048), dim3(256), 0, stream,
                           x, S64, T64, S32, T32, amap, idxb, pcTb, LUT, P5);
        hipLaunchKernelGGL(k_main_direct, dim3(B_ / 16), dim3(256), 0, stream,
                           idxb, LUT, out);
    }
}